// Round 3
// baseline (2172.523 us; speedup 1.0000x reference)
//
#include <hip/hip_runtime.h>
#include <stdint.h>

// ---- problem dims (BailingMoE: T=1024 H=2048 E=16 I=1408 S=2 topk=4) ----
// All tensors are FLOAT32 (reference dtype). fp32->bf16 conversion happens
// during LDS staging; MFMA is bf16 with fp32 accumulate.
#define T_TOK 1024
#define H_DIM 2048
#define E_NUM 16
#define I_DIM 1408
#define IS_DIM 2816   // I*S (shared intermediate half-width)
#define TOPK 4

#define BM 128
#define BN 128
#define BK 32

typedef unsigned short u16;
typedef __bf16 bf16x8 __attribute__((ext_vector_type(8)));
typedef float f32x4 __attribute__((ext_vector_type(4)));

__device__ __forceinline__ u16 f2bf(float f) {
  unsigned int v; __builtin_memcpy(&v, &f, 4);
  unsigned int lsb = (v >> 16) & 1u;
  v += 0x7fffu + lsb;   // RNE (finite values only)
  return (u16)(v >> 16);
}

__device__ __forceinline__ f32x4 mfma16(bf16x8 a, bf16x8 b, f32x4 c) {
  return __builtin_amdgcn_mfma_f32_16x16x32_bf16(a, b, c, 0, 0, 0);
}

// Stage a ROWSx32 fp32 tile (row stride ld) into LDS as bf16 [row][32].
// 256 threads, float4 loads, RNE convert, uint2 stores.
template <int NELEM>   // ROWS*32
__device__ __forceinline__ void stage_cvt(u16* lds, const float* __restrict__ g,
                                          int ld, int tid) {
#pragma unroll
  for (int e = 0; e < NELEM / 1024; ++e) {
    const int elem = e * 1024 + tid * 4;
    const int row = elem >> 5, col = elem & 31;
    float4 v = *(const float4*)(g + (size_t)row * ld + col);
    uint2 o;
    o.x = (unsigned)f2bf(v.x) | ((unsigned)f2bf(v.y) << 16);
    o.y = (unsigned)f2bf(v.z) | ((unsigned)f2bf(v.w) << 16);
    *(uint2*)(lds + elem) = o;
  }
}

// Stage a 128x32 bf16 tile (row stride ld elems) into LDS, plain copy.
__device__ __forceinline__ void stage_bf16(u16* lds, const u16* __restrict__ g,
                                           int ld, int tid) {
#pragma unroll
  for (int p = 0; p < 2; ++p) {
    const int elem = p * 2048 + tid * 8;
    const int row = elem >> 5, col = elem & 31;
    uint4 v = *(const uint4*)(g + (size_t)row * ld + col);
    *(uint4*)(lds + elem) = v;
  }
}

// ============================ router ============================
// fp32 throughout: logits = x @ gate_w^T; softmax; top-4 (first-index
// tie-break); renormalize. combine stays fp32 (astype(x.dtype) is a no-op).
__global__ __launch_bounds__(256) void router_kernel(
    const float* __restrict__ x, const float* __restrict__ gw,
    float* __restrict__ combine) {
  __shared__ float partial[256];
  __shared__ float logits[E_NUM];
  const int t = blockIdx.x, tid = threadIdx.x;
  const int e = tid >> 4, l16 = tid & 15;
  const float* xr = x + (size_t)t * H_DIM;
  const float* wr = gw + (size_t)e * H_DIM;
  float s = 0.f;
  for (int h = l16 * 4; h < H_DIM; h += 64) {
    float4 xv = *(const float4*)&xr[h];
    float4 wv = *(const float4*)&wr[h];
    s += xv.x * wv.x + xv.y * wv.y + xv.z * wv.z + xv.w * wv.w;
  }
  partial[tid] = s;
  __syncthreads();
  if (tid < E_NUM) {
    float tot = 0.f;
    for (int j = 0; j < 16; ++j) tot += partial[tid * 16 + j];
    logits[tid] = tot;
  }
  __syncthreads();
  if (tid == 0) {
    float p[E_NUM];
    float mx = -1e30f;
    for (int i = 0; i < E_NUM; ++i) mx = fmaxf(mx, logits[i]);
    float sum = 0.f;
    for (int i = 0; i < E_NUM; ++i) { p[i] = expf(logits[i] - mx); sum += p[i]; }
    float inv = 1.f / sum;
    for (int i = 0; i < E_NUM; ++i) p[i] *= inv;
    bool used[E_NUM];
    for (int i = 0; i < E_NUM; ++i) used[i] = false;
    int idx[TOPK]; float w4[TOPK]; float wsum = 0.f;
    for (int k = 0; k < TOPK; ++k) {
      int best = 0; float bv = -1.f;
      for (int i = 0; i < E_NUM; ++i)
        if (!used[i] && p[i] > bv) { bv = p[i]; best = i; }
      used[best] = true; idx[k] = best; w4[k] = bv; wsum += bv;
    }
    float outw[E_NUM];
    for (int i = 0; i < E_NUM; ++i) outw[i] = 0.f;
    float winv = 1.f / wsum;
    for (int k = 0; k < TOPK; ++k) outw[idx[k]] = w4[k] * winv;
    for (int i = 0; i < E_NUM; ++i) combine[(size_t)t * E_NUM + i] = outw[i];
  }
}

// ====================== gate_up + SiLU*mul ======================
// X:[T,H] fp32; W rows [N,K=H] fp32 (gate half at row 0, up half at nHalf).
// out = silu(g)*u (* combine[t,expert] if SCALE), stored bf16 into ws.
template <bool SCALE>
__global__ __launch_bounds__(256, 1) void gateup_silu_kernel(
    const float* __restrict__ X, const float* __restrict__ Wbase,
    size_t wStride, int nHalf, const float* __restrict__ combine,
    u16* __restrict__ OutBase, size_t oStride) {
  __shared__ u16 As[BM * BK];
  __shared__ u16 Wg[BN * BK];
  __shared__ u16 Wu[BN * BK];
  const int tid = threadIdx.x;
  const int wave = tid >> 6, lane = tid & 63;
  const int lane16 = lane & 15, quad = lane >> 4;
  const int wm = wave >> 1, wn = wave & 1;
  const int z = blockIdx.z;
  const int row0 = blockIdx.y * BM;
  const int n0 = blockIdx.x * BN;
  const float* W = Wbase + (size_t)z * wStride;
  const float* Wgp = W + (size_t)n0 * H_DIM;
  const float* Wup = W + (size_t)(nHalf + n0) * H_DIM;
  const float* Ap = X + (size_t)row0 * H_DIM;
  u16* Out = OutBase + (size_t)z * oStride;

  const f32x4 zero = {0.f, 0.f, 0.f, 0.f};
  f32x4 accg[4][4], accu[4][4];
#pragma unroll
  for (int i = 0; i < 4; ++i)
#pragma unroll
    for (int j = 0; j < 4; ++j) { accg[i][j] = zero; accu[i][j] = zero; }

  for (int k0 = 0; k0 < H_DIM; k0 += BK) {
    stage_cvt<BM * BK>(As, Ap + k0, H_DIM, tid);
    stage_cvt<BN * BK>(Wg, Wgp + k0, H_DIM, tid);
    stage_cvt<BN * BK>(Wu, Wup + k0, H_DIM, tid);
    __syncthreads();
    bf16x8 a[4], bg[4], bu[4];
#pragma unroll
    for (int i = 0; i < 4; ++i)
      a[i] = *(const bf16x8*)&As[(wm * 64 + i * 16 + lane16) * BK + quad * 8];
#pragma unroll
    for (int j = 0; j < 4; ++j) {
      bg[j] = *(const bf16x8*)&Wg[(wn * 64 + j * 16 + lane16) * BK + quad * 8];
      bu[j] = *(const bf16x8*)&Wu[(wn * 64 + j * 16 + lane16) * BK + quad * 8];
    }
#pragma unroll
    for (int i = 0; i < 4; ++i)
#pragma unroll
      for (int j = 0; j < 4; ++j) {
        accg[i][j] = mfma16(a[i], bg[j], accg[i][j]);
        accu[i][j] = mfma16(a[i], bu[j], accu[i][j]);
      }
    __syncthreads();
  }

  float cs[4][4];
  if (SCALE) {
#pragma unroll
    for (int i = 0; i < 4; ++i)
#pragma unroll
      for (int r = 0; r < 4; ++r) {
        int row = row0 + wm * 64 + i * 16 + quad * 4 + r;
        cs[i][r] = combine[(size_t)row * E_NUM + z];
      }
  }
#pragma unroll
  for (int i = 0; i < 4; ++i) {
#pragma unroll
    for (int j = 0; j < 4; ++j) {
      const int col = n0 + wn * 64 + j * 16 + lane16;
#pragma unroll
      for (int r = 0; r < 4; ++r) {
        const int row = row0 + wm * 64 + i * 16 + quad * 4 + r;
        float g = accg[i][j][r], u = accu[i][j][r];
        float act = g / (1.f + __expf(-g)) * u;
        if (SCALE) act *= cs[i][r];
        Out[(size_t)row * nHalf + col] = f2bf(act);
      }
    }
  }
}

// ===================== fused down projection =====================
// out[t,h] = act_s[t,:] @ shared_down[h,:] + sum_e act_r[e,t,:] @ w_down[e,h,:]
// acts bf16 in ws (pre-scaled by combine); weights fp32 (cvt during staging).
// BM=128 x BN=64 tiles -> grid 32x8 = 256 blocks, full K per block (z=1),
// fp32 result written directly to d_out.
#define DBN 64
#define KT_SHARED 88
#define KT_PER_EXP 44
#define KT_TOTAL 792

__global__ __launch_bounds__(256, 1) void down_fused_kernel(
    const u16* __restrict__ actS, const u16* __restrict__ actR,
    const float* __restrict__ Wsd, const float* __restrict__ Wd,
    float* __restrict__ out) {
  __shared__ u16 As[BM * BK];
  __shared__ u16 Bs[DBN * BK];
  const int tid = threadIdx.x;
  const int wave = tid >> 6, lane = tid & 63;
  const int lane16 = lane & 15, quad = lane >> 4;
  const int wm = wave >> 1, wn = wave & 1;  // 2x2 waves: 64 rows x 32 cols each
  const int row0 = blockIdx.y * BM;   // token tile
  const int col0 = blockIdx.x * DBN;  // hidden tile

  const f32x4 zero = {0.f, 0.f, 0.f, 0.f};
  f32x4 acc[4][2];
#pragma unroll
  for (int i = 0; i < 4; ++i)
#pragma unroll
    for (int j = 0; j < 2; ++j) acc[i][j] = zero;

  for (int kt = 0; kt < KT_TOTAL; ++kt) {
    const u16* ap; const float* wp; int lda, ldw;
    if (kt < KT_SHARED) {
      ap = actS + (size_t)row0 * IS_DIM + kt * BK;
      wp = Wsd + (size_t)col0 * IS_DIM + kt * BK;
      lda = IS_DIM; ldw = IS_DIM;
    } else {
      const int kk = kt - KT_SHARED;
      const int e = kk / KT_PER_EXP;
      const int ib = kk % KT_PER_EXP;
      ap = actR + ((size_t)e * T_TOK + row0) * I_DIM + ib * BK;
      wp = Wd + ((size_t)e * H_DIM + col0) * I_DIM + ib * BK;
      lda = I_DIM; ldw = I_DIM;
    }
    stage_bf16(As, ap, lda, tid);
    stage_cvt<DBN * BK>(Bs, wp, ldw, tid);
    __syncthreads();
    bf16x8 a[4], b[2];
#pragma unroll
    for (int i = 0; i < 4; ++i)
      a[i] = *(const bf16x8*)&As[(wm * 64 + i * 16 + lane16) * BK + quad * 8];
#pragma unroll
    for (int j = 0; j < 2; ++j)
      b[j] = *(const bf16x8*)&Bs[(wn * 32 + j * 16 + lane16) * BK + quad * 8];
#pragma unroll
    for (int i = 0; i < 4; ++i)
#pragma unroll
      for (int j = 0; j < 2; ++j) acc[i][j] = mfma16(a[i], b[j], acc[i][j]);
    __syncthreads();
  }

#pragma unroll
  for (int i = 0; i < 4; ++i) {
#pragma unroll
    for (int j = 0; j < 2; ++j) {
      const int col = col0 + wn * 32 + j * 16 + lane16;
#pragma unroll
      for (int r = 0; r < 4; ++r) {
        const int row = row0 + wm * 64 + i * 16 + quad * 4 + r;
        out[(size_t)row * H_DIM + col] = acc[i][j][r];
      }
    }
  }
}

// ============================ launch ============================
extern "C" void kernel_launch(void* const* d_in, const int* in_sizes, int n_in,
                              void* d_out, int out_size, void* d_ws,
                              size_t ws_size, hipStream_t stream) {
  const float* x = (const float*)d_in[0];           // [1024,2048]
  const float* gate_w = (const float*)d_in[1];      // [16,2048]
  const float* w_gate_up = (const float*)d_in[2];   // [16,2816,2048]
  const float* w_down = (const float*)d_in[3];      // [16,2048,1408]
  const float* shared_gu = (const float*)d_in[4];   // [5632,2048]
  const float* shared_down = (const float*)d_in[5]; // [2048,2816]
  float* out = (float*)d_out;

  char* ws = (char*)d_ws;
  float* combine = (float*)ws;              // 64 KiB fp32 [T,E]
  u16* actS = (u16*)(ws + 65536);           // 5.77 MB bf16 [T,2816]
  u16* actR = (u16*)(ws + 65536 + 5767168); // 46.1 MB bf16 [E,T,1408]
  // total ws usage: 51,970,048 B (~49.6 MiB)

  router_kernel<<<T_TOK, 256, 0, stream>>>(x, gate_w, combine);

  // shared experts gate_up + silu: N_half = 2816 -> 22 col tiles
  gateup_silu_kernel<false><<<dim3(IS_DIM / BN, T_TOK / BM, 1), 256, 0, stream>>>(
      x, shared_gu, 0, IS_DIM, nullptr, actS, 0);

  // routed gate_up + silu, scaled by combine: per expert, N_half=1408 -> 11 tiles
  gateup_silu_kernel<true><<<dim3(I_DIM / BN, T_TOK / BM, E_NUM), 256, 0, stream>>>(
      x, w_gate_up, (size_t)2 * I_DIM * H_DIM, I_DIM, combine, actR,
      (size_t)T_TOK * I_DIM);

  // fused down projection (shared + all experts), fp32 out direct
  down_fused_kernel<<<dim3(H_DIM / DBN, T_TOK / BM, 1), 256, 0, stream>>>(
      actS, actR, shared_down, w_down, out);
}

// Round 4
// 1209.103 us; speedup vs baseline: 1.7968x; 1.7968x over previous
//
#include <hip/hip_runtime.h>
#include <stdint.h>

// ---- problem dims (BailingMoE: T=1024 H=2048 E=16 I=1408 S=2 topk=4) ----
// All tensors FLOAT32. fp32->bf16 RNE conversion during LDS staging; MFMA is
// bf16 with fp32 accumulate. Routed experts computed SPARSELY (top-4 only)
// via per-expert gather lists.
#define T_TOK 1024
#define H_DIM 2048
#define E_NUM 16
#define I_DIM 1408
#define IS_DIM 2816   // I*S (shared intermediate half-width)
#define TOPK 4

#define BM 128
#define BN 128
#define BK 32

typedef unsigned short u16;
typedef __bf16 bf16x8 __attribute__((ext_vector_type(8)));
typedef float f32x4 __attribute__((ext_vector_type(4)));

__device__ __forceinline__ u16 f2bf(float f) {
  unsigned int v; __builtin_memcpy(&v, &f, 4);
  unsigned int lsb = (v >> 16) & 1u;
  v += 0x7fffu + lsb;   // RNE (finite values only)
  return (u16)(v >> 16);
}

__device__ __forceinline__ f32x4 mfma16(bf16x8 a, bf16x8 b, f32x4 c) {
  return __builtin_amdgcn_mfma_f32_16x16x32_bf16(a, b, c, 0, 0, 0);
}

// Stage a ROWSx32 fp32 tile (row stride ld) into LDS as bf16 [row][32].
template <int NELEM>   // ROWS*32
__device__ __forceinline__ void stage_cvt(u16* lds, const float* __restrict__ g,
                                          int ld, int tid) {
#pragma unroll
  for (int e = 0; e < NELEM / 1024; ++e) {
    const int elem = e * 1024 + tid * 4;
    const int row = elem >> 5, col = elem & 31;
    float4 v = *(const float4*)(g + (size_t)row * ld + col);
    uint2 o;
    o.x = (unsigned)f2bf(v.x) | ((unsigned)f2bf(v.y) << 16);
    o.y = (unsigned)f2bf(v.z) | ((unsigned)f2bf(v.w) << 16);
    *(uint2*)(lds + elem) = o;
  }
}

// Stage a 128x32 bf16 tile (row stride ld elems) into LDS, plain copy.
__device__ __forceinline__ void stage_bf16(u16* lds, const u16* __restrict__ g,
                                           int ld, int tid) {
#pragma unroll
  for (int p = 0; p < 2; ++p) {
    const int elem = p * 2048 + tid * 8;
    const int row = elem >> 5, col = elem & 31;
    uint4 v = *(const uint4*)(g + (size_t)row * ld + col);
    *(uint4*)(lds + elem) = v;
  }
}

// ============================ router ============================
__global__ __launch_bounds__(256) void router_kernel(
    const float* __restrict__ x, const float* __restrict__ gw,
    float* __restrict__ combine, int* __restrict__ topk_idx) {
  __shared__ float partial[256];
  __shared__ float logits[E_NUM];
  const int t = blockIdx.x, tid = threadIdx.x;
  const int e = tid >> 4, l16 = tid & 15;
  const float* xr = x + (size_t)t * H_DIM;
  const float* wr = gw + (size_t)e * H_DIM;
  float s = 0.f;
  for (int h = l16 * 4; h < H_DIM; h += 64) {
    float4 xv = *(const float4*)&xr[h];
    float4 wv = *(const float4*)&wr[h];
    s += xv.x * wv.x + xv.y * wv.y + xv.z * wv.z + xv.w * wv.w;
  }
  partial[tid] = s;
  __syncthreads();
  if (tid < E_NUM) {
    float tot = 0.f;
    for (int j = 0; j < 16; ++j) tot += partial[tid * 16 + j];
    logits[tid] = tot;
  }
  __syncthreads();
  if (tid == 0) {
    float p[E_NUM];
    float mx = -1e30f;
    for (int i = 0; i < E_NUM; ++i) mx = fmaxf(mx, logits[i]);
    float sum = 0.f;
    for (int i = 0; i < E_NUM; ++i) { p[i] = expf(logits[i] - mx); sum += p[i]; }
    float inv = 1.f / sum;
    for (int i = 0; i < E_NUM; ++i) p[i] *= inv;
    bool used[E_NUM];
    for (int i = 0; i < E_NUM; ++i) used[i] = false;
    int idx[TOPK]; float w4[TOPK]; float wsum = 0.f;
    for (int k = 0; k < TOPK; ++k) {
      int best = 0; float bv = -1.f;
      for (int i = 0; i < E_NUM; ++i)
        if (!used[i] && p[i] > bv) { bv = p[i]; best = i; }
      used[best] = true; idx[k] = best; w4[k] = bv; wsum += bv;
    }
    float outw[E_NUM];
    for (int i = 0; i < E_NUM; ++i) outw[i] = 0.f;
    float winv = 1.f / wsum;
    for (int k = 0; k < TOPK; ++k) {
      outw[idx[k]] = w4[k] * winv;
      topk_idx[t * TOPK + k] = idx[k];
    }
    for (int i = 0; i < E_NUM; ++i) combine[(size_t)t * E_NUM + i] = outw[i];
  }
}

// =================== per-expert gather-list build ===================
// Single block. list[e][p] = token id for p < cnt[e]; padded (dup of last)
// up to cntPad[e] = ceil(cnt/BM)*BM.
__global__ __launch_bounds__(256) void assign_kernel(
    const int* __restrict__ topk_idx, int* __restrict__ list,
    int* __restrict__ cnt, int* __restrict__ cntPad) {
  __shared__ int lcnt[E_NUM], lcur[E_NUM];
  const int tid = threadIdx.x;
  if (tid < E_NUM) { lcnt[tid] = 0; lcur[tid] = 0; }
  __syncthreads();
  for (int t = tid; t < T_TOK; t += 256)
    for (int k = 0; k < TOPK; ++k)
      atomicAdd(&lcnt[topk_idx[t * TOPK + k]], 1);
  __syncthreads();
  for (int t = tid; t < T_TOK; t += 256)
    for (int k = 0; k < TOPK; ++k) {
      int e = topk_idx[t * TOPK + k];
      int p = atomicAdd(&lcur[e], 1);
      list[e * T_TOK + p] = t;
    }
  __syncthreads();
  if (tid < E_NUM) {
    int c = lcnt[tid];
    int cp = (c + BM - 1) / BM * BM;
    cnt[tid] = c;
    cntPad[tid] = cp;
    int last = (c > 0) ? list[tid * T_TOK + c - 1] : 0;
    for (int p = c; p < cp; ++p) list[tid * T_TOK + p] = last;
  }
}

// =================== shared-expert gate_up + SiLU*mul ===================
__global__ __launch_bounds__(256, 1) void gateup_shared_kernel(
    const float* __restrict__ X, const float* __restrict__ W,
    u16* __restrict__ Out) {
  __shared__ u16 As[BM * BK];
  __shared__ u16 Wg[BN * BK];
  __shared__ u16 Wu[BN * BK];
  const int tid = threadIdx.x;
  const int wave = tid >> 6, lane = tid & 63;
  const int lane16 = lane & 15, quad = lane >> 4;
  const int wm = wave >> 1, wn = wave & 1;
  const int row0 = blockIdx.y * BM;
  const int n0 = blockIdx.x * BN;
  const float* Wgp = W + (size_t)n0 * H_DIM;
  const float* Wup = W + (size_t)(IS_DIM + n0) * H_DIM;
  const float* Ap = X + (size_t)row0 * H_DIM;

  const f32x4 zero = {0.f, 0.f, 0.f, 0.f};
  f32x4 accg[4][4], accu[4][4];
#pragma unroll
  for (int i = 0; i < 4; ++i)
#pragma unroll
    for (int j = 0; j < 4; ++j) { accg[i][j] = zero; accu[i][j] = zero; }

  for (int k0 = 0; k0 < H_DIM; k0 += BK) {
    stage_cvt<BM * BK>(As, Ap + k0, H_DIM, tid);
    stage_cvt<BN * BK>(Wg, Wgp + k0, H_DIM, tid);
    stage_cvt<BN * BK>(Wu, Wup + k0, H_DIM, tid);
    __syncthreads();
    bf16x8 a[4], bg[4], bu[4];
#pragma unroll
    for (int i = 0; i < 4; ++i)
      a[i] = *(const bf16x8*)&As[(wm * 64 + i * 16 + lane16) * BK + quad * 8];
#pragma unroll
    for (int j = 0; j < 4; ++j) {
      bg[j] = *(const bf16x8*)&Wg[(wn * 64 + j * 16 + lane16) * BK + quad * 8];
      bu[j] = *(const bf16x8*)&Wu[(wn * 64 + j * 16 + lane16) * BK + quad * 8];
    }
#pragma unroll
    for (int i = 0; i < 4; ++i)
#pragma unroll
      for (int j = 0; j < 4; ++j) {
        accg[i][j] = mfma16(a[i], bg[j], accg[i][j]);
        accu[i][j] = mfma16(a[i], bu[j], accu[i][j]);
      }
    __syncthreads();
  }
#pragma unroll
  for (int i = 0; i < 4; ++i)
#pragma unroll
    for (int j = 0; j < 4; ++j) {
      const int col = n0 + wn * 64 + j * 16 + lane16;
#pragma unroll
      for (int r = 0; r < 4; ++r) {
        const int row = row0 + wm * 64 + i * 16 + quad * 4 + r;
        float g = accg[i][j][r], u = accu[i][j][r];
        Out[(size_t)row * IS_DIM + col] = f2bf(g / (1.f + __expf(-g)) * u);
      }
    }
}

// =================== routed gate_up + SiLU*mul (gathered) ===================
// Block: expert e, token-tile pos0 (gathered rows), I-tile n0.
// Writes act * combine into actR[e][pos][*] (padded rows written too).
__global__ __launch_bounds__(256, 1) void gateup_routed_kernel(
    const float* __restrict__ X, const float* __restrict__ Wgu,
    const float* __restrict__ combine, const int* __restrict__ list,
    const int* __restrict__ cntPad, u16* __restrict__ actR) {
  __shared__ u16 As[BM * BK];
  __shared__ u16 Wg[BN * BK];
  __shared__ u16 Wu[BN * BK];
  __shared__ int ltok[BM];
  const int e = blockIdx.z;
  const int pos0 = blockIdx.y * BM;
  if (pos0 >= cntPad[e]) return;
  const int tid = threadIdx.x;
  const int n0 = blockIdx.x * BN;
  if (tid < BM) ltok[tid] = list[e * T_TOK + pos0 + tid];
  __syncthreads();
  const int wave = tid >> 6, lane = tid & 63;
  const int lane16 = lane & 15, quad = lane >> 4;
  const int wm = wave >> 1, wn = wave & 1;
  const float* Wgp = Wgu + (size_t)e * (2 * I_DIM * H_DIM) + (size_t)n0 * H_DIM;
  const float* Wup = Wgp + (size_t)I_DIM * H_DIM;

  // fixed gather rows for this thread's A-staging slots
  int grow[4];
#pragma unroll
  for (int q = 0; q < 4; ++q) grow[q] = ltok[q * 32 + (tid >> 3)];
  const int colA = (tid & 7) * 4;

  const f32x4 zero = {0.f, 0.f, 0.f, 0.f};
  f32x4 accg[4][4], accu[4][4];
#pragma unroll
  for (int i = 0; i < 4; ++i)
#pragma unroll
    for (int j = 0; j < 4; ++j) { accg[i][j] = zero; accu[i][j] = zero; }

  for (int k0 = 0; k0 < H_DIM; k0 += BK) {
#pragma unroll
    for (int q = 0; q < 4; ++q) {   // gathered A stage
      float4 v = *(const float4*)(X + (size_t)grow[q] * H_DIM + k0 + colA);
      uint2 o;
      o.x = (unsigned)f2bf(v.x) | ((unsigned)f2bf(v.y) << 16);
      o.y = (unsigned)f2bf(v.z) | ((unsigned)f2bf(v.w) << 16);
      *(uint2*)&As[q * 1024 + tid * 4] = o;
    }
    stage_cvt<BN * BK>(Wg, Wgp + k0, H_DIM, tid);
    stage_cvt<BN * BK>(Wu, Wup + k0, H_DIM, tid);
    __syncthreads();
    bf16x8 a[4], bg[4], bu[4];
#pragma unroll
    for (int i = 0; i < 4; ++i)
      a[i] = *(const bf16x8*)&As[(wm * 64 + i * 16 + lane16) * BK + quad * 8];
#pragma unroll
    for (int j = 0; j < 4; ++j) {
      bg[j] = *(const bf16x8*)&Wg[(wn * 64 + j * 16 + lane16) * BK + quad * 8];
      bu[j] = *(const bf16x8*)&Wu[(wn * 64 + j * 16 + lane16) * BK + quad * 8];
    }
#pragma unroll
    for (int i = 0; i < 4; ++i)
#pragma unroll
      for (int j = 0; j < 4; ++j) {
        accg[i][j] = mfma16(a[i], bg[j], accg[i][j]);
        accu[i][j] = mfma16(a[i], bu[j], accu[i][j]);
      }
    __syncthreads();
  }
#pragma unroll
  for (int i = 0; i < 4; ++i)
#pragma unroll
    for (int j = 0; j < 4; ++j) {
      const int col = n0 + wn * 64 + j * 16 + lane16;
#pragma unroll
      for (int r = 0; r < 4; ++r) {
        const int rl = wm * 64 + i * 16 + quad * 4 + r;   // local row
        float g = accg[i][j][r], u = accu[i][j][r];
        float act = g / (1.f + __expf(-g)) * u;
        act *= combine[(size_t)ltok[rl] * E_NUM + e];
        actR[((size_t)e * T_TOK + pos0 + rl) * I_DIM + col] = f2bf(act);
      }
    }
}

// =================== shared down: out = actS @ Wsd^T (fp32 direct) ===========
__global__ __launch_bounds__(256, 1) void down_shared_kernel(
    const u16* __restrict__ actS, const float* __restrict__ Wsd,
    float* __restrict__ out) {
  __shared__ u16 As[BM * BK];
  __shared__ u16 Bs[BN * BK];
  const int tid = threadIdx.x;
  const int wave = tid >> 6, lane = tid & 63;
  const int lane16 = lane & 15, quad = lane >> 4;
  const int wm = wave >> 1, wn = wave & 1;
  const int row0 = blockIdx.y * BM;
  const int col0 = blockIdx.x * BN;

  const f32x4 zero = {0.f, 0.f, 0.f, 0.f};
  f32x4 acc[4][4];
#pragma unroll
  for (int i = 0; i < 4; ++i)
#pragma unroll
    for (int j = 0; j < 4; ++j) acc[i][j] = zero;

  for (int k0 = 0; k0 < IS_DIM; k0 += BK) {
    stage_bf16(As, actS + (size_t)row0 * IS_DIM + k0, IS_DIM, tid);
    stage_cvt<BN * BK>(Bs, Wsd + (size_t)col0 * IS_DIM + k0, IS_DIM, tid);
    __syncthreads();
    bf16x8 a[4], b[4];
#pragma unroll
    for (int i = 0; i < 4; ++i)
      a[i] = *(const bf16x8*)&As[(wm * 64 + i * 16 + lane16) * BK + quad * 8];
#pragma unroll
    for (int j = 0; j < 4; ++j)
      b[j] = *(const bf16x8*)&Bs[(wn * 64 + j * 16 + lane16) * BK + quad * 8];
#pragma unroll
    for (int i = 0; i < 4; ++i)
#pragma unroll
      for (int j = 0; j < 4; ++j) acc[i][j] = mfma16(a[i], b[j], acc[i][j]);
    __syncthreads();
  }
#pragma unroll
  for (int i = 0; i < 4; ++i)
#pragma unroll
    for (int j = 0; j < 4; ++j) {
      const int col = col0 + wn * 64 + j * 16 + lane16;
#pragma unroll
      for (int r = 0; r < 4; ++r) {
        const int row = row0 + wm * 64 + i * 16 + quad * 4 + r;
        out[(size_t)row * H_DIM + col] = acc[i][j][r];
      }
    }
}

// ============ routed down: scatter atomicAdd into out (after shared) =========
__global__ __launch_bounds__(256, 1) void down_routed_kernel(
    const u16* __restrict__ actR, const float* __restrict__ Wd,
    const int* __restrict__ list, const int* __restrict__ cnt,
    const int* __restrict__ cntPad, float* __restrict__ out) {
  __shared__ u16 As[BM * BK];
  __shared__ u16 Bs[BN * BK];
  __shared__ int ltok[BM];
  const int e = blockIdx.z;
  const int pos0 = blockIdx.y * BM;
  if (pos0 >= cntPad[e]) return;
  const int tid = threadIdx.x;
  const int col0 = blockIdx.x * BN;
  if (tid < BM) ltok[tid] = list[e * T_TOK + pos0 + tid];
  const int c = cnt[e];
  const int wave = tid >> 6, lane = tid & 63;
  const int lane16 = lane & 15, quad = lane >> 4;
  const int wm = wave >> 1, wn = wave & 1;
  const u16* Ap = actR + ((size_t)e * T_TOK + pos0) * I_DIM;
  const float* Bp = Wd + ((size_t)e * H_DIM + col0) * I_DIM;

  const f32x4 zero = {0.f, 0.f, 0.f, 0.f};
  f32x4 acc[4][4];
#pragma unroll
  for (int i = 0; i < 4; ++i)
#pragma unroll
    for (int j = 0; j < 4; ++j) acc[i][j] = zero;

  for (int k0 = 0; k0 < I_DIM; k0 += BK) {
    stage_bf16(As, Ap + k0, I_DIM, tid);
    stage_cvt<BN * BK>(Bs, Bp + k0, I_DIM, tid);
    __syncthreads();
    bf16x8 a[4], b[4];
#pragma unroll
    for (int i = 0; i < 4; ++i)
      a[i] = *(const bf16x8*)&As[(wm * 64 + i * 16 + lane16) * BK + quad * 8];
#pragma unroll
    for (int j = 0; j < 4; ++j)
      b[j] = *(const bf16x8*)&Bs[(wn * 64 + j * 16 + lane16) * BK + quad * 8];
#pragma unroll
    for (int i = 0; i < 4; ++i)
#pragma unroll
      for (int j = 0; j < 4; ++j) acc[i][j] = mfma16(a[i], b[j], acc[i][j]);
    __syncthreads();
  }
#pragma unroll
  for (int i = 0; i < 4; ++i)
#pragma unroll
    for (int j = 0; j < 4; ++j) {
      const int col = col0 + wn * 64 + j * 16 + lane16;
#pragma unroll
      for (int r = 0; r < 4; ++r) {
        const int rl = wm * 64 + i * 16 + quad * 4 + r;
        if (pos0 + rl < c)
          atomicAdd(&out[(size_t)ltok[rl] * H_DIM + col], acc[i][j][r]);
      }
    }
}

// ============================ launch ============================
extern "C" void kernel_launch(void* const* d_in, const int* in_sizes, int n_in,
                              void* d_out, int out_size, void* d_ws,
                              size_t ws_size, hipStream_t stream) {
  const float* x = (const float*)d_in[0];           // [1024,2048]
  const float* gate_w = (const float*)d_in[1];      // [16,2048]
  const float* w_gate_up = (const float*)d_in[2];   // [16,2816,2048]
  const float* w_down = (const float*)d_in[3];      // [16,2048,1408]
  const float* shared_gu = (const float*)d_in[4];   // [5632,2048]
  const float* shared_down = (const float*)d_in[5]; // [2048,2816]
  float* out = (float*)d_out;

  char* ws = (char*)d_ws;
  float* combine = (float*)ws;                 // 64 KiB fp32 [T,E]
  int* topk_idx = (int*)(ws + 65536);          // 16 KiB [T,4]
  int* list = (int*)(ws + 81920);              // 64 KiB [E,1024]
  int* cnt = (int*)(ws + 147456);              // 64 B
  int* cntPad = (int*)(ws + 147520);           // 64 B
  u16* actS = (u16*)(ws + 147584);             // 5.77 MB bf16 [T,2816]
  u16* actR = (u16*)(ws + 147584 + 5767168);   // 46.1 MB bf16 [E,1024,1408]
  // total ws usage: 52,052,096 B (~49.6 MiB, same as proven round-3)

  router_kernel<<<T_TOK, 256, 0, stream>>>(x, gate_w, combine, topk_idx);
  assign_kernel<<<1, 256, 0, stream>>>(topk_idx, list, cnt, cntPad);

  gateup_shared_kernel<<<dim3(IS_DIM / BN, T_TOK / BM), 256, 0, stream>>>(
      x, shared_gu, actS);

  gateup_routed_kernel<<<dim3(I_DIM / BN, T_TOK / BM, E_NUM), 256, 0, stream>>>(
      x, w_gate_up, combine, list, cntPad, actR);

  down_shared_kernel<<<dim3(H_DIM / BN, T_TOK / BM), 256, 0, stream>>>(
      actS, shared_down, out);

  down_routed_kernel<<<dim3(H_DIM / BN, T_TOK / BM, E_NUM), 256, 0, stream>>>(
      actR, w_down, list, cnt, cntPad, out);
}